// Round 12
// baseline (52.878 us; speedup 1.0000x reference)
//
#include <hip/hip_runtime.h>

#define NB 32
#define NC 64
#define NO 128
#define NK 9
#define NL 4096

#define SLICES 16           // colsum slices per batch == blocks per batch
#define SL (NL / SLICES)    // 256 l per slice
#define OSPLIT 4
#define OPB (NO / OSPLIT)   // 32 output channels per block
#define LTILE 1024          // 256 threads * 4 floats
#define NLT (NL / LTILE)    // 4 l-tiles

#define CNT_STRIDE 32       // one 128-B cacheline per batch counter

typedef float vfloat4 __attribute__((ext_vector_type(4)));
typedef float vfloat2 __attribute__((ext_vector_type(2)));

// One fused kernel, 512 blocks (2/CU, all co-resident).
// Block (b, j): phase A computes colsum slice j of batch b, release-publishes
// it; then RELAXED-polls the padded per-batch counter (no cache invalidate
// per poll) and issues ONE acquire fence before phase B reads colsum.
__global__ __launch_bounds__(256) void gmconv_fused(
    const float* __restrict__ x, const float* __restrict__ wc,
    const float* __restrict__ ev, const float* __restrict__ bias,
    const int* __restrict__ idx, float* __restrict__ colsum,
    int* __restrict__ cnt, float* __restrict__ out)
{
    __shared__ vfloat4 part[4][64];
    __shared__ float red[4];
    __shared__ float invS[OPB];
    __shared__ vfloat2 cbS[OPB];   // {evinv/||w_o||, bias_o}
    __shared__ float csS[NL];      // 16 KB staged colsum[b]

    const int bid = blockIdx.x;
    const int j  = bid & (SLICES - 1);   // slice within batch
    const int b  = bid >> 4;             // batch
    const int og = j & (OSPLIT - 1);     // o-group for phase B
    const int lt = j >> 2;               // l-tile for phase B
    const int t  = threadIdx.x;

    // ---- phase-B operand prefetch (independent of A; hides under x loads) --
    const int l0 = lt * LTILE + t * 4;
    const vfloat4 e4 = *reinterpret_cast<const vfloat4*>(ev + l0);
    int4 iv[NK];
#pragma unroll
    for (int k = 0; k < NK; ++k)
        iv[k] = *reinterpret_cast<const int4*>(idx + k * NL + l0);

    // ---- phase A: colsum slice (b, j); 1 KB contiguous per wave-instr -----
    // plain loads (not nt): x stays L3-resident across replays
    const int col = t & 63;
    const int cg  = t >> 6;
    const float* xp = x + (size_t)b * NC * NL + (size_t)cg * 16 * NL
                        + j * SL + col * 4;
    vfloat4 xacc = (vfloat4){0.f, 0.f, 0.f, 0.f};
#pragma unroll
    for (int i = 0; i < 16; ++i)
        xacc += *reinterpret_cast<const vfloat4*>(xp + (size_t)i * NL);

    // block-local evinv (ev is L2/L3-resident; overlaps x loads)
    float s = 0.f;
#pragma unroll
    for (int r = 0; r < 4; ++r) {
        vfloat4 v = *reinterpret_cast<const vfloat4*>(ev + (r * 256 + t) * 4);
        s += v.x * v.x + v.y * v.y + v.z * v.z + v.w * v.w;
    }
#pragma unroll
    for (int off = 32; off > 0; off >>= 1) s += __shfl_down(s, off, 64);
    if ((t & 63) == 0) red[t >> 6] = s;

    // per-row weight inv-norms for this block's 32 output channels
    if (t < OPB) {
        const int o = og * OPB + t;
        float ss = 0.f;
#pragma unroll
        for (int k = 0; k < NK; ++k) { const float w = wc[o * NK + k]; ss += w * w; }
        invS[t] = rsqrtf(ss);
    }
    part[cg][col] = xacc;
    __syncthreads();

    const float evinv = rsqrtf(red[0] + red[1] + red[2] + red[3]);
    if (t < OPB)
        cbS[t] = (vfloat2){invS[t] * evinv, bias[og * OPB + t]};
    if (t < 64) {
        vfloat4 sl = part[0][t] + part[1][t] + part[2][t] + part[3][t];
        *reinterpret_cast<vfloat4*>(colsum + (size_t)b * NL + j * SL + t * 4) = sl;
    }
    __syncthreads();

    // ---- publish slice, then wait for all 16 slices of batch b ----
    // RELAXED polls: agent-scope atomic load reads the coherent point (sc1)
    // WITHOUT emitting a cache invalidate per iteration (R10's poison).
    if (t == 0) {
        __hip_atomic_fetch_add(&cnt[b * CNT_STRIDE], 1, __ATOMIC_RELEASE,
                               __HIP_MEMORY_SCOPE_AGENT);
        while (__hip_atomic_load(&cnt[b * CNT_STRIDE], __ATOMIC_RELAXED,
                                 __HIP_MEMORY_SCOPE_AGENT) < SLICES)
            __builtin_amdgcn_s_sleep(8);
    }
    __syncthreads();
    // ONE acquire fence per thread before reading other blocks' colsum slices
    __builtin_amdgcn_fence(__ATOMIC_ACQUIRE, "agent");

    // ---- phase B: stage colsum[b] -> LDS ----
    const float* __restrict__ csg = colsum + (size_t)b * NL;
#pragma unroll
    for (int r = 0; r < 4; ++r) {
        const int jj = (r * 256 + t) * 4;
        *reinterpret_cast<vfloat4*>(&csS[jj]) =
            *reinterpret_cast<const vfloat4*>(csg + jj);
    }
    __syncthreads();

    // gathers, pre-scaled by raw ev (norms folded into c_o)
    const float ex = e4.x, ey = e4.y, ez = e4.z, ew = e4.w;
    vfloat2 g01[NK], g23[NK];
#pragma unroll
    for (int k = 0; k < NK; ++k) {
        g01[k] = (vfloat2){csS[iv[k].x] * ex, csS[iv[k].y] * ey};
        g23[k] = (vfloat2){csS[iv[k].z] * ez, csS[iv[k].w] * ew};
    }

    const int obase = og * OPB;
    float* op = out + ((size_t)b * NO + obase) * NL + l0;
#pragma unroll
    for (int o = 0; o < OPB; ++o) {
        const float* __restrict__ wr = wc + (obase + o) * NK;  // uniform -> s_load
        vfloat2 a01 = (vfloat2){0.f, 0.f};
        vfloat2 a23 = (vfloat2){0.f, 0.f};
#pragma unroll
        for (int k = 0; k < NK; ++k) {
            const float w = wr[k];            // SGPR broadcast -> v_pk_fma_f32
            a01 += w * g01[k];
            a23 += w * g23[k];
        }
        const vfloat2 cb = cbS[o];            // {c_o, bias_o}, LDS broadcast
        const vfloat4 r = (vfloat4){a01.x * cb.x + cb.y, a01.y * cb.x + cb.y,
                                    a23.x * cb.x + cb.y, a23.y * cb.x + cb.y};
        __builtin_nontemporal_store(r, reinterpret_cast<vfloat4*>(op));
        op += NL;
    }
}

extern "C" void kernel_launch(void* const* d_in, const int* in_sizes, int n_in,
                              void* d_out, int out_size, void* d_ws, size_t ws_size,
                              hipStream_t stream) {
    const float* x    = (const float*)d_in[0];   // [32,64,1,4096]
    const float* wc   = (const float*)d_in[1];   // [128,1,9]
    const float* ev   = (const float*)d_in[2];   // [1,4096]
    const float* bias = (const float*)d_in[3];   // [128]
    const int*   idx  = (const int*)d_in[4];     // [9,4096]
    float* out = (float*)d_out;                  // [32,128,1,4096]

    int*   cnt    = (int*)d_ws;                        // 32 padded counters
    float* colsum = (float*)d_ws + NB * CNT_STRIDE;    // NB*NL floats

    // deterministic flag reset each call (graph-capturable memset node)
    hipMemsetAsync(cnt, 0, NB * CNT_STRIDE * sizeof(int), stream);

    hipLaunchKernelGGL(gmconv_fused, dim3(NB * SLICES), dim3(256), 0, stream,
                       x, wc, ev, bias, idx, colsum, cnt, out);
}

// Round 13
// 34.759 us; speedup vs baseline: 1.5213x; 1.5213x over previous
//
#include <hip/hip_runtime.h>

#define NB 32
#define NC 64
#define NO 128
#define NK 9
#define NL 4096

#define SLICES 16           // colsum slices per batch == blocks per batch
#define SL (NL / SLICES)    // 256 l per slice
#define OSPLIT 4
#define OPB (NO / OSPLIT)   // 32 output channels per block
#define LTILE 1024          // 256 threads * 4 floats
#define NLT (NL / LTILE)    // 4 l-tiles

#define CNT_STRIDE 32       // one 128-B cacheline per batch counter

typedef float vfloat4 __attribute__((ext_vector_type(4)));
typedef float vfloat2 __attribute__((ext_vector_type(2)));

// One fused kernel, 512 blocks (2/CU, all co-resident).
// Producer/consumer with ZERO cache-maintenance instructions:
//  - colsum slices are stored with relaxed AGENT-scope atomic stores
//    (write-through to the coherent point; no buffer_wbl2),
//  - wave 0 waits vmcnt(0) then relaxed fetch_add publishes the slice,
//  - consumers poll relaxed and re-read colsum with relaxed AGENT-scope
//    atomic loads (coherent-point reads; no buffer_inv).
__global__ __launch_bounds__(256) void gmconv_fused(
    const float* __restrict__ x, const float* __restrict__ wc,
    const float* __restrict__ ev, const float* __restrict__ bias,
    const int* __restrict__ idx, float* __restrict__ colsum,
    int* __restrict__ cnt, float* __restrict__ out)
{
    __shared__ vfloat4 part[4][64];
    __shared__ float red[4];
    __shared__ float invS[OPB];
    __shared__ vfloat2 cbS[OPB];   // {evinv/||w_o||, bias_o}
    __shared__ float csS[NL];      // 16 KB staged colsum[b]

    const int bid = blockIdx.x;
    const int j  = bid & (SLICES - 1);   // slice within batch
    const int b  = bid >> 4;             // batch
    const int og = j & (OSPLIT - 1);     // o-group for phase B
    const int lt = j >> 2;               // l-tile for phase B
    const int t  = threadIdx.x;

    // ---- phase-B operand prefetch (independent of A; hides under x loads) --
    const int l0 = lt * LTILE + t * 4;
    const vfloat4 e4 = *reinterpret_cast<const vfloat4*>(ev + l0);
    int4 iv[NK];
#pragma unroll
    for (int k = 0; k < NK; ++k)
        iv[k] = *reinterpret_cast<const int4*>(idx + k * NL + l0);

    // ---- phase A: colsum slice (b, j); 1 KB contiguous per wave-instr -----
    const int col = t & 63;
    const int cg  = t >> 6;
    const float* xp = x + (size_t)b * NC * NL + (size_t)cg * 16 * NL
                        + j * SL + col * 4;
    vfloat4 xacc = (vfloat4){0.f, 0.f, 0.f, 0.f};
#pragma unroll
    for (int i = 0; i < 16; ++i)
        xacc += *reinterpret_cast<const vfloat4*>(xp + (size_t)i * NL);

    // block-local evinv (ev is L2/L3-resident; overlaps x loads)
    float s = 0.f;
#pragma unroll
    for (int r = 0; r < 4; ++r) {
        vfloat4 v = *reinterpret_cast<const vfloat4*>(ev + (r * 256 + t) * 4);
        s += v.x * v.x + v.y * v.y + v.z * v.z + v.w * v.w;
    }
#pragma unroll
    for (int off = 32; off > 0; off >>= 1) s += __shfl_down(s, off, 64);
    if ((t & 63) == 0) red[t >> 6] = s;

    // per-row weight inv-norms for this block's 32 output channels
    if (t < OPB) {
        const int o = og * OPB + t;
        float ss = 0.f;
#pragma unroll
        for (int k = 0; k < NK; ++k) { const float w = wc[o * NK + k]; ss += w * w; }
        invS[t] = rsqrtf(ss);
    }
    part[cg][col] = xacc;
    __syncthreads();

    const float evinv = rsqrtf(red[0] + red[1] + red[2] + red[3]);
    if (t < OPB)
        cbS[t] = (vfloat2){invS[t] * evinv, bias[og * OPB + t]};

    // slice store: relaxed agent-scope atomic stores = write-through to the
    // coherent point (no dirty L2 line, hence no wbl2 needed to publish).
    if (t < 64) {
        vfloat4 sl = part[0][t] + part[1][t] + part[2][t] + part[3][t];
        float* cp = colsum + (size_t)b * NL + j * SL + t * 4;
        __hip_atomic_store(cp + 0, sl.x, __ATOMIC_RELAXED, __HIP_MEMORY_SCOPE_AGENT);
        __hip_atomic_store(cp + 1, sl.y, __ATOMIC_RELAXED, __HIP_MEMORY_SCOPE_AGENT);
        __hip_atomic_store(cp + 2, sl.z, __ATOMIC_RELAXED, __HIP_MEMORY_SCOPE_AGENT);
        __hip_atomic_store(cp + 3, sl.w, __ATOMIC_RELAXED, __HIP_MEMORY_SCOPE_AGENT);
        // all storer lanes (t<64) are wave 0: one wave-level vmcnt(0) makes
        // every colsum store globally visible before t==0 publishes.
        asm volatile("s_waitcnt vmcnt(0)" ::: "memory");
        if (t == 0) {
            __hip_atomic_fetch_add(&cnt[b * CNT_STRIDE], 1, __ATOMIC_RELAXED,
                                   __HIP_MEMORY_SCOPE_AGENT);
            while (__hip_atomic_load(&cnt[b * CNT_STRIDE], __ATOMIC_RELAXED,
                                     __HIP_MEMORY_SCOPE_AGENT) < SLICES)
                __builtin_amdgcn_s_sleep(2);
        }
    }
    __syncthreads();

    // ---- phase B: stage colsum[b] -> LDS via coherent-point loads ----
    const float* __restrict__ csg = colsum + (size_t)b * NL;
#pragma unroll
    for (int r = 0; r < NL / 256; ++r) {
        const int jj = r * 256 + t;
        csS[jj] = __hip_atomic_load(const_cast<float*>(csg) + jj,
                                    __ATOMIC_RELAXED, __HIP_MEMORY_SCOPE_AGENT);
    }
    __syncthreads();

    // gathers, pre-scaled by raw ev (norms folded into c_o)
    const float ex = e4.x, ey = e4.y, ez = e4.z, ew = e4.w;
    vfloat2 g01[NK], g23[NK];
#pragma unroll
    for (int k = 0; k < NK; ++k) {
        g01[k] = (vfloat2){csS[iv[k].x] * ex, csS[iv[k].y] * ey};
        g23[k] = (vfloat2){csS[iv[k].z] * ez, csS[iv[k].w] * ew};
    }

    const int obase = og * OPB;
    float* op = out + ((size_t)b * NO + obase) * NL + l0;
#pragma unroll
    for (int o = 0; o < OPB; ++o) {
        const float* __restrict__ wr = wc + (obase + o) * NK;  // uniform -> s_load
        vfloat2 a01 = (vfloat2){0.f, 0.f};
        vfloat2 a23 = (vfloat2){0.f, 0.f};
#pragma unroll
        for (int k = 0; k < NK; ++k) {
            const float w = wr[k];            // SGPR broadcast -> v_pk_fma_f32
            a01 += w * g01[k];
            a23 += w * g23[k];
        }
        const vfloat2 cb = cbS[o];            // {c_o, bias_o}, LDS broadcast
        const vfloat4 r = (vfloat4){a01.x * cb.x + cb.y, a01.y * cb.x + cb.y,
                                    a23.x * cb.x + cb.y, a23.y * cb.x + cb.y};
        __builtin_nontemporal_store(r, reinterpret_cast<vfloat4*>(op));
        op += NL;
    }
}

extern "C" void kernel_launch(void* const* d_in, const int* in_sizes, int n_in,
                              void* d_out, int out_size, void* d_ws, size_t ws_size,
                              hipStream_t stream) {
    const float* x    = (const float*)d_in[0];   // [32,64,1,4096]
    const float* wc   = (const float*)d_in[1];   // [128,1,9]
    const float* ev   = (const float*)d_in[2];   // [1,4096]
    const float* bias = (const float*)d_in[3];   // [128]
    const int*   idx  = (const int*)d_in[4];     // [9,4096]
    float* out = (float*)d_out;                  // [32,128,1,4096]

    int*   cnt    = (int*)d_ws;                        // 32 padded counters
    float* colsum = (float*)d_ws + NB * CNT_STRIDE;    // NB*NL floats

    // deterministic flag reset each call (graph-capturable memset node)
    hipMemsetAsync(cnt, 0, NB * CNT_STRIDE * sizeof(int), stream);

    hipLaunchKernelGGL(gmconv_fused, dim3(NB * SLICES), dim3(256), 0, stream,
                       x, wc, ev, bias, idx, colsum, cnt, out);
}

// Round 14
// 23.444 us; speedup vs baseline: 2.2555x; 1.4826x over previous
//
#include <hip/hip_runtime.h>

#define NB 32
#define NC 64
#define NO 128
#define NK 9
#define NL 4096

#define OSPLIT 4
#define OPB (NO / OSPLIT)   // 32 output channels per block
#define LTILE 1024          // 256 threads * 4 floats
#define NLT (NL / LTILE)    // 4 l-tiles

typedef float vfloat4 __attribute__((ext_vector_type(4)));
typedef float vfloat2 __attribute__((ext_vector_type(2)));

// ---------- kernel 1: colsum[b][l] = sum_i x[b][i][l] ----------
// 512 blocks (2/CU): (b, lt), lt in [0,16) covering 256 l each.
// col = t&63 -> each wave-instruction reads 1 KB CONTIGUOUS from one channel.
// block 0 additionally computes evinv and the normalized wcn -> ws.
__global__ __launch_bounds__(256) void colsum_kernel(
    const float* __restrict__ x, const float* __restrict__ ev,
    const float* __restrict__ wc,
    float* __restrict__ colsum, float* __restrict__ evinv,
    float* __restrict__ wcn_ws)
{
    __shared__ vfloat4 part[4][64];
    __shared__ float red[4];

    const int bid = blockIdx.x;
    const int t = threadIdx.x;

    if (bid == 0) {
        // inv L2 norm of err_vector
        float s = 0.f;
#pragma unroll
        for (int r = 0; r < NL / 256; ++r) {
            float v = ev[r * 256 + t];
            s += v * v;
        }
#pragma unroll
        for (int off = 32; off > 0; off >>= 1) s += __shfl_down(s, off, 64);
        if ((t & 63) == 0) red[t >> 6] = s;
        // normalized weight_coeff rows -> workspace (read back via s_load in main)
        if (t < NO) {
            float w[NK]; float ss = 0.f;
#pragma unroll
            for (int k = 0; k < NK; ++k) { w[k] = wc[t * NK + k]; ss += w[k] * w[k]; }
            const float inv = rsqrtf(ss);
#pragma unroll
            for (int k = 0; k < NK; ++k) wcn_ws[t * NK + k] = w[k] * inv;
        }
        __syncthreads();
        if (t == 0) evinv[0] = rsqrtf(red[0] + red[1] + red[2] + red[3]);
    }

    const int b  = bid >> 4;          // 32 batches
    const int lt = bid & 15;          // 16 tiles of 256 l
    const int col = t & 63;           // float4 column in tile (64 per wave)
    const int cg  = t >> 6;           // channel group (4 groups of 16)
    const int l = lt * 256 + col * 4;

    const float* xp = x + (size_t)b * NC * NL + (size_t)cg * 16 * NL + l;
    vfloat4 acc = (vfloat4){0.f, 0.f, 0.f, 0.f};
#pragma unroll
    for (int i = 0; i < 16; ++i) {
        vfloat4 v = __builtin_nontemporal_load(
            reinterpret_cast<const vfloat4*>(xp + (size_t)i * NL));
        acc += v;
    }
    part[cg][col] = acc;
    __syncthreads();
    if (t < 64) {
        vfloat4 s = part[0][t] + part[1][t] + part[2][t] + part[3][t];
        *reinterpret_cast<vfloat4*>(colsum + (size_t)b * NL + lt * 256 + t * 4) = s;
    }
}

// ---------- kernel 2: out[b,o,l] = evn[l] * sum_k wcn[o,k]*colsum[b,idx[k,l]] + bias[o]
// 512 blocks (2/CU): (b, lt, og). Weights/bias via uniform s_load.
// idx/ev loads hoisted BEFORE the staging barrier to overlap their latency.
// PLAIN out stores (vs R8's nt): L2-buffered writeback for better DRAM
// scheduling — the only change vs the 22.92 us R8 kernel.
__global__ __launch_bounds__(256) void gmconv_main_kernel(
    const float* __restrict__ wcn, const float* __restrict__ ev,
    const float* __restrict__ bias, const int* __restrict__ idx,
    const float* __restrict__ colsum, const float* __restrict__ evinv_p,
    float* __restrict__ out)
{
    __shared__ float csS[NL];        // 16 KB staged colsum[b]

    const int bid = blockIdx.x;
    const int og = bid & (OSPLIT - 1);        // 4 o-groups
    const int lt = (bid >> 2) & (NLT - 1);    // 4 l-tiles
    const int b  = bid >> 4;                  // 32 batches
    const int t  = threadIdx.x;

    const float evinv = evinv_p[0];           // uniform -> s_load, early
    const int l0 = lt * LTILE + t * 4;

    // issue independent loads BEFORE staging so their latency overlaps it
    const vfloat4 e4 = *reinterpret_cast<const vfloat4*>(ev + l0);
    int4 iv[NK];
#pragma unroll
    for (int k = 0; k < NK; ++k)
        iv[k] = *reinterpret_cast<const int4*>(idx + k * NL + l0);

    // stage colsum[b] -> LDS (linear float4, conflict-free)
    const float* __restrict__ csg = colsum + (size_t)b * NL;
#pragma unroll
    for (int r = 0; r < NL / (4 * 256); ++r) {
        const int j = (r * 256 + t) * 4;
        *reinterpret_cast<vfloat4*>(&csS[j]) =
            *reinterpret_cast<const vfloat4*>(csg + j);
    }
    __syncthreads();

    const float ex = e4.x * evinv, ey = e4.y * evinv,
                ez = e4.z * evinv, ew = e4.w * evinv;

    // gather from LDS, pre-scaled by normalized err_vector
    vfloat2 g01[NK], g23[NK];
#pragma unroll
    for (int k = 0; k < NK; ++k) {
        g01[k] = (vfloat2){csS[iv[k].x] * ex, csS[iv[k].y] * ey};
        g23[k] = (vfloat2){csS[iv[k].z] * ez, csS[iv[k].w] * ew};
    }

    const int obase = og * OPB;
    float* op = out + ((size_t)b * NO + obase) * NL + l0;
#pragma unroll
    for (int o = 0; o < OPB; ++o) {
        const float* __restrict__ wr = wcn + (obase + o) * NK;  // uniform address
        vfloat2 a01 = (vfloat2){0.f, 0.f};
        vfloat2 a23 = (vfloat2){0.f, 0.f};
#pragma unroll
        for (int k = 0; k < NK; ++k) {
            const float w = wr[k];            // s_load, SGPR broadcast -> v_pk_fma_f32
            a01 += w * g01[k];
            a23 += w * g23[k];
        }
        const float bb = bias[obase + o];     // uniform -> s_load
        const vfloat4 r = (vfloat4){a01.x + bb, a01.y + bb, a23.x + bb, a23.y + bb};
        *reinterpret_cast<vfloat4*>(op) = r;  // plain store (was nt in R8)
        op += NL;
    }
}

extern "C" void kernel_launch(void* const* d_in, const int* in_sizes, int n_in,
                              void* d_out, int out_size, void* d_ws, size_t ws_size,
                              hipStream_t stream) {
    const float* x    = (const float*)d_in[0];   // [32,64,1,4096]
    const float* wc   = (const float*)d_in[1];   // [128,1,9]
    const float* ev   = (const float*)d_in[2];   // [1,4096]
    const float* bias = (const float*)d_in[3];   // [128]
    const int*   idx  = (const int*)d_in[4];     // [9,4096]
    float* out = (float*)d_out;                  // [32,128,1,4096]

    float* wsf    = (float*)d_ws;
    float* evinv  = wsf;           // 1 float
    float* wcn_ws = wsf + 64;      // 128*9 = 1152 floats
    float* colsum = wsf + 1344;    // NB*NL floats (aligned)

    hipLaunchKernelGGL(colsum_kernel, dim3(NB * 16), dim3(256), 0, stream,
                       x, ev, wc, colsum, evinv, wcn_ws);
    hipLaunchKernelGGL(gmconv_main_kernel, dim3(NB * NLT * OSPLIT), dim3(256), 0,
                       stream, wcn_ws, ev, bias, idx, colsum, evinv, out);
}

// Round 15
// 22.651 us; speedup vs baseline: 2.3345x; 1.0350x over previous
//
#include <hip/hip_runtime.h>

#define NB 32
#define NC 64
#define NO 128
#define NK 9
#define NL 4096

#define OSPLIT 4
#define OPB (NO / OSPLIT)   // 32 output channels per block
#define LTILE 1024          // 256 threads * 4 floats
#define NLT (NL / LTILE)    // 4 l-tiles

typedef float vfloat4 __attribute__((ext_vector_type(4)));
typedef float vfloat2 __attribute__((ext_vector_type(2)));

// ---------- kernel 1: colsum[b][l] = sum_i x[b][i][l] ----------
// 512 blocks (2/CU): (b, lt), lt in [0,16) covering 256 l each.
// col = t&63 -> each wave-instruction reads 1 KB CONTIGUOUS from one channel.
// block 0 additionally computes evinv and the normalized wcn -> ws.
__global__ __launch_bounds__(256) void colsum_kernel(
    const float* __restrict__ x, const float* __restrict__ ev,
    const float* __restrict__ wc,
    float* __restrict__ colsum, float* __restrict__ evinv,
    float* __restrict__ wcn_ws)
{
    __shared__ vfloat4 part[4][64];
    __shared__ float red[4];

    const int bid = blockIdx.x;
    const int t = threadIdx.x;

    if (bid == 0) {
        // inv L2 norm of err_vector
        float s = 0.f;
#pragma unroll
        for (int r = 0; r < NL / 256; ++r) {
            float v = ev[r * 256 + t];
            s += v * v;
        }
#pragma unroll
        for (int off = 32; off > 0; off >>= 1) s += __shfl_down(s, off, 64);
        if ((t & 63) == 0) red[t >> 6] = s;
        // normalized weight_coeff rows -> workspace (read back via s_load in main)
        if (t < NO) {
            float w[NK]; float ss = 0.f;
#pragma unroll
            for (int k = 0; k < NK; ++k) { w[k] = wc[t * NK + k]; ss += w[k] * w[k]; }
            const float inv = rsqrtf(ss);
#pragma unroll
            for (int k = 0; k < NK; ++k) wcn_ws[t * NK + k] = w[k] * inv;
        }
        __syncthreads();
        if (t == 0) evinv[0] = rsqrtf(red[0] + red[1] + red[2] + red[3]);
    }

    const int b  = bid >> 4;          // 32 batches
    const int lt = bid & 15;          // 16 tiles of 256 l
    const int col = t & 63;           // float4 column in tile (64 per wave)
    const int cg  = t >> 6;           // channel group (4 groups of 16)
    const int l = lt * 256 + col * 4;

    const float* xp = x + (size_t)b * NC * NL + (size_t)cg * 16 * NL + l;
    vfloat4 acc = (vfloat4){0.f, 0.f, 0.f, 0.f};
#pragma unroll
    for (int i = 0; i < 16; ++i) {
        vfloat4 v = __builtin_nontemporal_load(
            reinterpret_cast<const vfloat4*>(xp + (size_t)i * NL));
        acc += v;
    }
    part[cg][col] = acc;
    __syncthreads();
    if (t < 64) {
        vfloat4 s = part[0][t] + part[1][t] + part[2][t] + part[3][t];
        *reinterpret_cast<vfloat4*>(colsum + (size_t)b * NL + lt * 256 + t * 4) = s;
    }
}

// ---------- kernel 2: out[b,o,l] = evn[l] * sum_k wcn[o,k]*colsum[b,idx[k,l]] + bias[o]
// 512 blocks (2/CU): (b, lt, og). Weights/bias via uniform s_load.
// idx/ev loads hoisted BEFORE the staging barrier to overlap their latency.
// nt out stores (write-once; best-measured R8 configuration).
__global__ __launch_bounds__(256) void gmconv_main_kernel(
    const float* __restrict__ wcn, const float* __restrict__ ev,
    const float* __restrict__ bias, const int* __restrict__ idx,
    const float* __restrict__ colsum, const float* __restrict__ evinv_p,
    float* __restrict__ out)
{
    __shared__ float csS[NL];        // 16 KB staged colsum[b]

    const int bid = blockIdx.x;
    const int og = bid & (OSPLIT - 1);        // 4 o-groups
    const int lt = (bid >> 2) & (NLT - 1);    // 4 l-tiles
    const int b  = bid >> 4;                  // 32 batches
    const int t  = threadIdx.x;

    const float evinv = evinv_p[0];           // uniform -> s_load, early
    const int l0 = lt * LTILE + t * 4;

    // issue independent loads BEFORE staging so their latency overlaps it
    const vfloat4 e4 = *reinterpret_cast<const vfloat4*>(ev + l0);
    int4 iv[NK];
#pragma unroll
    for (int k = 0; k < NK; ++k)
        iv[k] = *reinterpret_cast<const int4*>(idx + k * NL + l0);

    // stage colsum[b] -> LDS (linear float4, conflict-free)
    const float* __restrict__ csg = colsum + (size_t)b * NL;
#pragma unroll
    for (int r = 0; r < NL / (4 * 256); ++r) {
        const int j = (r * 256 + t) * 4;
        *reinterpret_cast<vfloat4*>(&csS[j]) =
            *reinterpret_cast<const vfloat4*>(csg + j);
    }
    __syncthreads();

    const float ex = e4.x * evinv, ey = e4.y * evinv,
                ez = e4.z * evinv, ew = e4.w * evinv;

    // gather from LDS, pre-scaled by normalized err_vector
    vfloat2 g01[NK], g23[NK];
#pragma unroll
    for (int k = 0; k < NK; ++k) {
        g01[k] = (vfloat2){csS[iv[k].x] * ex, csS[iv[k].y] * ey};
        g23[k] = (vfloat2){csS[iv[k].z] * ez, csS[iv[k].w] * ew};
    }

    const int obase = og * OPB;
    float* op = out + ((size_t)b * NO + obase) * NL + l0;
#pragma unroll
    for (int o = 0; o < OPB; ++o) {
        const float* __restrict__ wr = wcn + (obase + o) * NK;  // uniform address
        vfloat2 a01 = (vfloat2){0.f, 0.f};
        vfloat2 a23 = (vfloat2){0.f, 0.f};
#pragma unroll
        for (int k = 0; k < NK; ++k) {
            const float w = wr[k];            // s_load, SGPR broadcast -> v_pk_fma_f32
            a01 += w * g01[k];
            a23 += w * g23[k];
        }
        const float bb = bias[obase + o];     // uniform -> s_load
        const vfloat4 r = (vfloat4){a01.x + bb, a01.y + bb, a23.x + bb, a23.y + bb};
        __builtin_nontemporal_store(r, reinterpret_cast<vfloat4*>(op));
        op += NL;
    }
}

extern "C" void kernel_launch(void* const* d_in, const int* in_sizes, int n_in,
                              void* d_out, int out_size, void* d_ws, size_t ws_size,
                              hipStream_t stream) {
    const float* x    = (const float*)d_in[0];   // [32,64,1,4096]
    const float* wc   = (const float*)d_in[1];   // [128,1,9]
    const float* ev   = (const float*)d_in[2];   // [1,4096]
    const float* bias = (const float*)d_in[3];   // [128]
    const int*   idx  = (const int*)d_in[4];     // [9,4096]
    float* out = (float*)d_out;                  // [32,128,1,4096]

    float* wsf    = (float*)d_ws;
    float* evinv  = wsf;           // 1 float
    float* wcn_ws = wsf + 64;      // 128*9 = 1152 floats
    float* colsum = wsf + 1344;    // NB*NL floats (aligned)

    hipLaunchKernelGGL(colsum_kernel, dim3(NB * 16), dim3(256), 0, stream,
                       x, ev, wc, colsum, evinv, wcn_ws);
    hipLaunchKernelGGL(gmconv_main_kernel, dim3(NB * NLT * OSPLIT), dim3(256), 0,
                       stream, wcn_ws, ev, bias, idx, colsum, evinv, out);
}